// Round 3
// baseline (351.264 us; speedup 1.0000x reference)
//
#include <hip/hip_runtime.h>
#include <stdint.h>

// Problem constants: B=8, N=2048, F_in=F_out=512
#define NB 8
#define NN 2048
#define NF 512
#define TOTN (NB * NN)   // 16384 nodes total

typedef unsigned short u16;
typedef short bf16x8 __attribute__((ext_vector_type(8)));
typedef float f32x4 __attribute__((ext_vector_type(4)));

__device__ __forceinline__ u16 f2bf(float x) {
  unsigned u = __float_as_uint(x);
  unsigned r = 0x7FFFu + ((u >> 16) & 1u);
  return (u16)((u + r) >> 16);
}

__device__ __forceinline__ void gl2lds16(const void* g, void* l) {
  // async global->LDS, 16B per lane; LDS dst = wave-uniform base + lane*16
  __builtin_amdgcn_global_load_lds((const __attribute__((address_space(1))) void*)g,
                                   (__attribute__((address_space(3))) void*)l,
                                   16, 0, 0);
}

// ---------------------------------------------------------------------------
// K1: convert text (8.4M fp32) -> bf16, and W -> W^T bf16.
// ---------------------------------------------------------------------------
__global__ __launch_bounds__(256) void conv_kernel(
    const float* __restrict__ text, const float* __restrict__ W,
    u16* __restrict__ text_bf, u16* __restrict__ Wt) {
  int blk = blockIdx.x;
  if (blk < 8192) {
    int idx = blk * 256 + threadIdx.x;
    float4 v = ((const float4*)text)[idx];
    ushort4 o;
    o.x = f2bf(v.x); o.y = f2bf(v.y); o.z = f2bf(v.z); o.w = f2bf(v.w);
    ((ushort4*)text_bf)[idx] = o;
  } else {
    int t = (blk - 8192) * 256 + threadIdx.x;
    int o = t >> 9, f = t & 511;
    Wt[o * NF + f] = f2bf(W[f * NF + o]);
  }
}

// ---------------------------------------------------------------------------
// K2: GEMM1 hiddenT[o][node] = sum_f Wt[o][f]*text_bf[node][f] + bias[o]
// Fused epilogue: s[n] += sum_m h*a_src[m], d[n] += sum_m h*a_dst[m]
// (cross-quad shfl reduce, one atomicAdd per (wave,n); s/d pre-zeroed).
// ---------------------------------------------------------------------------
__global__ __launch_bounds__(256) void gemm1_kernel(
    const u16* __restrict__ A,   // Wt [512][512]
    const u16* __restrict__ Bt,  // text_bf [16384][512]
    const float* __restrict__ bias, const float* __restrict__ a_src,
    const float* __restrict__ a_dst, u16* __restrict__ hT,
    float* __restrict__ s, float* __restrict__ d) {
  __shared__ u16 Alds[128 * 32];
  __shared__ u16 Blds[128 * 32];

  const int bn = blockIdx.x, bm = blockIdx.y;
  const int t = threadIdx.x, wave = t >> 6, lane = t & 63;
  const int wm = (wave >> 1) * 64, wn = (wave & 1) * 64;

  f32x4 acc[4][4];
#pragma unroll
  for (int i = 0; i < 4; ++i)
#pragma unroll
    for (int j = 0; j < 4; ++j) acc[i][j] = (f32x4){0.f, 0.f, 0.f, 0.f};

  const int rowA0 = bm * 128, rowB0 = bn * 128;
  const int srow = (lane >> 2);
  const int scol = (lane & 3) * 8;

  for (int kt = 0; kt < NF; kt += 32) {
#pragma unroll
    for (int q = 0; q < 2; ++q) {
      int r = wave * 32 + q * 16;
      gl2lds16(A + (size_t)(rowA0 + r + srow) * NF + (kt + scol), &Alds[r * 32]);
    }
#pragma unroll
    for (int q = 0; q < 2; ++q) {
      int r = wave * 32 + q * 16;
      gl2lds16(Bt + (size_t)(rowB0 + r + srow) * NF + (kt + scol), &Blds[r * 32]);
    }
    __syncthreads();

    const int fr = lane & 15;
    const int k0 = (lane >> 4) * 8;
    bf16x8 af[4], bfr[4];
#pragma unroll
    for (int i = 0; i < 4; ++i)
      af[i] = *(const bf16x8*)&Alds[(wm + i * 16 + fr) * 32 + k0];
#pragma unroll
    for (int j = 0; j < 4; ++j)
      bfr[j] = *(const bf16x8*)&Blds[(wn + j * 16 + fr) * 32 + k0];
#pragma unroll
    for (int i = 0; i < 4; ++i)
#pragma unroll
      for (int j = 0; j < 4; ++j)
        acc[i][j] = __builtin_amdgcn_mfma_f32_16x16x32_bf16(af[i], bfr[j],
                                                            acc[i][j], 0, 0, 0);
    __syncthreads();
  }

  const int quad = lane >> 4, ln16 = lane & 15;
  float sa[4] = {0.f, 0.f, 0.f, 0.f}, da[4] = {0.f, 0.f, 0.f, 0.f};
#pragma unroll
  for (int i = 0; i < 4; ++i) {
    int m0 = bm * 128 + wm + i * 16 + quad * 4;
#pragma unroll
    for (int r = 0; r < 4; ++r) {
      int m = m0 + r;
      float bv = bias[m];
      float asv = a_src[m], adv = a_dst[m];
#pragma unroll
      for (int j = 0; j < 4; ++j) {
        int n = bn * 128 + wn + j * 16 + ln16;
        float h = acc[i][j][r] + bv;
        hT[(size_t)m * TOTN + n] = f2bf(h);
        sa[j] = fmaf(h, asv, sa[j]);
        da[j] = fmaf(h, adv, da[j]);
      }
    }
  }
#pragma unroll
  for (int j = 0; j < 4; ++j) {
    float v = sa[j] + __shfl_xor(sa[j], 16, 64);
    v += __shfl_xor(v, 32, 64);
    float w2 = da[j] + __shfl_xor(da[j], 16, 64);
    w2 += __shfl_xor(w2, 32, 64);
    if (quad == 0) {
      int n = bn * 128 + wn + j * 16 + ln16;
      atomicAdd(&s[n], v);
      atomicAdd(&d[n], w2);
    }
  }
}

// ---------------------------------------------------------------------------
// K3 (fused): out[z,i,o] = (1/l_i)*sum_j exp(lrelu(s_i+d_j))·[!adj]·hT[o][z*N+j]
// 32(i) x 256(o) block tile, 4 waves, BK=32, grid (64,2,8)=1024 blocks,
// 4 blocks/CU. XOR-swizzled LDS (conflict-free b128 frag reads; staging
// permutes the per-lane GLOBAL address so global_load_lds stays contiguous).
// Depth-2 register prefetch of adj/d rows.
// ---------------------------------------------------------------------------
__global__ __launch_bounds__(256, 4) void fused_attn_kernel(
    const int* __restrict__ adj, const float* __restrict__ s,
    const float* __restrict__ d, const u16* __restrict__ hT,
    float* __restrict__ out) {
  __shared__ u16 Plds[2 * 512];    // 32 rows (2 chunks of 16), swizzled, 2KB
  __shared__ u16 Blds[16 * 512];   // 256 o-rows (16 chunks), swizzled, 16KB
  __shared__ float lpart[32 * 8];
  __shared__ float linv_lds[32];

  const int z = blockIdx.z;
  const int oh = blockIdx.y;           // o-half
  const int i0 = blockIdx.x * 32;
  const int o0 = oh * 256;
  const int t = threadIdx.x, wave = t >> 6, lane = t & 63;
  const int quad = lane >> 4, ln16 = lane & 15;

  // P-generation mapping: 8 threads/row, 4 j each
  const int pr = t >> 3;               // 0..31
  const int pj = (t & 7) * 4;
  const float si = s[z * NN + i0 + pr];
  const int* arow = adj + (size_t)(z * NN + i0 + pr) * NN;
  const float* db = d + z * NN;

  // B staging: lane -> (row-in-chunk sr, swizzled quarter sq)
  const int sr = lane >> 2;
  const int sq = (lane & 3) ^ ((sr >> 1) & 3);

  f32x4 acc[2][4];
#pragma unroll
  for (int i = 0; i < 2; ++i)
#pragma unroll
    for (int j = 0; j < 4; ++j) acc[i][j] = (f32x4){0.f, 0.f, 0.f, 0.f};

  // depth-2 prefetch: invariant entering iter kt: (a0,dv0)=data(kt), (a1,dv1)=data(kt+32)
  int4 a0 = *(const int4*)&arow[pj];
  float4 dv0 = *(const float4*)&db[pj];
  int4 a1 = *(const int4*)&arow[32 + pj];
  float4 dv1 = *(const float4*)&db[32 + pj];

  float lsum = 0.f;
  const int fslot = ln16 * 4 + (quad ^ ((ln16 >> 1) & 3));  // frag-read slot

  for (int kt = 0; kt < NN; kt += 32) {
    // P from current regs
    float x0 = si + dv0.x, x1 = si + dv0.y, x2 = si + dv0.z, x3 = si + dv0.w;
    x0 = fmaxf(x0, 0.2f * x0); x1 = fmaxf(x1, 0.2f * x1);
    x2 = fmaxf(x2, 0.2f * x2); x3 = fmaxf(x3, 0.2f * x3);
    float p0 = a0.x ? 0.f : __expf(x0);
    float p1 = a0.y ? 0.f : __expf(x1);
    float p2 = a0.z ? 0.f : __expf(x2);
    float p3 = a0.w ? 0.f : __expf(x3);
    lsum += (p0 + p1) + (p2 + p3);
    ushort4 pk;
    pk.x = f2bf(p0); pk.y = f2bf(p1); pk.z = f2bf(p2); pk.w = f2bf(p3);

    __syncthreads();  // (1) everyone done reading frags of previous iter

    // swizzled P write: row pr, 8B at quarter pj>>3, byte-off (pj&7)*2
    {
      int rc = pr & 15, ch = pr >> 4;
      int slot = rc * 4 + ((pj >> 3) ^ ((rc >> 1) & 3));
      *(ushort4*)((char*)Plds + ch * 1024 + slot * 16 + (pj & 7) * 2) = pk;
    }
    // stage B tile: 16 chunks of 16 o-rows; lane L fetches (sr, sq)
#pragma unroll
    for (int c = 0; c < 4; ++c) {
      int ch = c * 4 + wave;
      gl2lds16(hT + (size_t)(o0 + ch * 16 + sr) * TOTN + z * NN + kt + sq * 8,
               &Blds[ch * 512]);
    }
    __syncthreads();  // (2) drain staging (vmcnt+lgkm)

    // prefetch kt+64 (issued AFTER barrier so its latency overlaps MFMA)
    a0 = a1; dv0 = dv1;
    if (kt + 64 < NN) {
      a1 = *(const int4*)&arow[kt + 64 + pj];
      dv1 = *(const float4*)&db[kt + 64 + pj];
    }

    // frags + MFMA: wave tile 32(i) x 64(o)
    bf16x8 af[2], bfr[4];
#pragma unroll
    for (int i = 0; i < 2; ++i)
      af[i] = *(const bf16x8*)((const char*)Plds + i * 1024 + fslot * 16);
#pragma unroll
    for (int j = 0; j < 4; ++j) {
      int ch = (wave * 64 + j * 16) >> 4;   // ln16 is row-in-chunk
      bfr[j] = *(const bf16x8*)((const char*)Blds + ch * 1024 + fslot * 16);
    }
#pragma unroll
    for (int i = 0; i < 2; ++i)
#pragma unroll
      for (int j = 0; j < 4; ++j)
        acc[i][j] = __builtin_amdgcn_mfma_f32_16x16x32_bf16(af[i], bfr[j],
                                                            acc[i][j], 0, 0, 0);
  }

  // row sums -> 1/l (each block covers the FULL j range, so sums are complete)
  lpart[pr * 8 + (t & 7)] = lsum;
  __syncthreads();
  if (t < 32) {
    const float* lp = &lpart[t * 8];
    float tot = ((lp[0] + lp[1]) + (lp[2] + lp[3])) +
                ((lp[4] + lp[5]) + (lp[6] + lp[7]));
    linv_lds[t] = 1.0f / tot;
  }
  __syncthreads();

  // epilogue: C/D layout col=lane&15, row=quad*4+reg
#pragma unroll
  for (int i = 0; i < 2; ++i) {
#pragma unroll
    for (int r = 0; r < 4; ++r) {
      int m = i * 16 + quad * 4 + r;
      float sc = linv_lds[m];
      size_t base = (size_t)(z * NN + i0 + m) * NF;
#pragma unroll
      for (int j = 0; j < 4; ++j) {
        int o = o0 + wave * 64 + j * 16 + ln16;
        out[base + o] = acc[i][j][r] * sc;
      }
    }
  }
}

// ---------------------------------------------------------------------------
// launch
// ---------------------------------------------------------------------------
extern "C" void kernel_launch(void* const* d_in, const int* in_sizes, int n_in,
                              void* d_out, int out_size, void* d_ws,
                              size_t ws_size, hipStream_t stream) {
  const float* text  = (const float*)d_in[0];   // [8,2048,512] fp32
  const int*   adj   = (const int*)d_in[1];     // [8,2048,2048] int32
  const float* W     = (const float*)d_in[2];   // [512,512] fp32
  const float* bias  = (const float*)d_in[3];   // [512] fp32
  const float* a_src = (const float*)d_in[4];   // [512] fp32
  const float* a_dst = (const float*)d_in[5];   // [512] fp32
  float* out = (float*)d_out;                   // [8,2048,512] fp32

  // ws layout (bytes)
  char* ws = (char*)d_ws;
  u16*   text_bf = (u16*)(ws + 0);              // 16,777,216
  u16*   Wt      = (u16*)(ws + 16777216);       //    524,288
  u16*   hT      = (u16*)(ws + 17301504);       // 16,777,216  [512][16384]
  float* s       = (float*)(ws + 34078720);     //     65,536
  float* d       = (float*)(ws + 34144256);     //     65,536

  // zero s,d for atomic accumulation (contiguous 128KB)
  hipMemsetAsync(s, 0, 131072, stream);

  conv_kernel<<<9216, 256, 0, stream>>>(text, W, text_bf, Wt);

  gemm1_kernel<<<dim3(128, 4, 1), 256, 0, stream>>>(Wt, text_bf, bias, a_src,
                                                    a_dst, hT, s, d);

  fused_attn_kernel<<<dim3(NN / 32, 2, NB), 256, 0, stream>>>(adj, s, d, hT, out);
}

// Round 4
// 301.364 us; speedup vs baseline: 1.1656x; 1.1656x over previous
//
#include <hip/hip_runtime.h>
#include <stdint.h>

// Problem constants: B=8, N=2048, F_in=F_out=512
#define NB 8
#define NN 2048
#define NF 512
#define TOTN (NB * NN)   // 16384 nodes total

typedef unsigned short u16;
typedef short bf16x8 __attribute__((ext_vector_type(8)));
typedef float f32x4 __attribute__((ext_vector_type(4)));

__device__ __forceinline__ u16 f2bf(float x) {
  unsigned u = __float_as_uint(x);
  unsigned r = 0x7FFFu + ((u >> 16) & 1u);
  return (u16)((u + r) >> 16);
}

__device__ __forceinline__ void gl2lds16(const void* g, void* l) {
  // async global->LDS, 16B per lane; LDS dst = wave-uniform base + lane*16
  __builtin_amdgcn_global_load_lds((const __attribute__((address_space(1))) void*)g,
                                   (__attribute__((address_space(3))) void*)l,
                                   16, 0, 0);
}

// slab swizzle: within a 16-row chunk, data (row rc, k-quarter q) lives at
// slot = rc*4 + (q ^ ((rc>>1)&3)), 16 B per slot.  (verified conflict-free R3)

// ---------------------------------------------------------------------------
// K1: convert text (8.4M fp32) -> bf16, and W -> W^T bf16.
// ---------------------------------------------------------------------------
__global__ __launch_bounds__(256) void conv_kernel(
    const float* __restrict__ text, const float* __restrict__ W,
    u16* __restrict__ text_bf, u16* __restrict__ Wt) {
  int blk = blockIdx.x;
  if (blk < 8192) {
    int idx = blk * 256 + threadIdx.x;
    float4 v = ((const float4*)text)[idx];
    ushort4 o;
    o.x = f2bf(v.x); o.y = f2bf(v.y); o.z = f2bf(v.z); o.w = f2bf(v.w);
    ((ushort4*)text_bf)[idx] = o;
  } else {
    int t = (blk - 8192) * 256 + threadIdx.x;
    int o = t >> 9, f = t & 511;
    Wt[o * NF + f] = f2bf(W[f * NF + o]);
  }
}

// ---------------------------------------------------------------------------
// K2: pack adj (int32 0/1) -> bitmask, 32 elems/thread. 134 MB -> 4 MB.
// bm layout: [node_row 16384][word 64] u32, linear == adj row-major / 32.
// ---------------------------------------------------------------------------
__global__ __launch_bounds__(256) void pack_kernel(
    const int* __restrict__ adj, uint32_t* __restrict__ bm) {
  int gid = blockIdx.x * 256 + threadIdx.x;   // 1,048,576 threads
  const int4* p = (const int4*)(adj + (size_t)gid * 32);
  uint32_t bits = 0;
#pragma unroll
  for (int c = 0; c < 8; ++c) {
    int4 a = p[c];
    bits |= (uint32_t)(a.x != 0) << (c * 4 + 0);
    bits |= (uint32_t)(a.y != 0) << (c * 4 + 1);
    bits |= (uint32_t)(a.z != 0) << (c * 4 + 2);
    bits |= (uint32_t)(a.w != 0) << (c * 4 + 3);
  }
  bm[gid] = bits;
}

// ---------------------------------------------------------------------------
// K3: GEMM1 hidden[o][node] -> pre-swizzled slabs + fused s/d score epilogue.
// hS layout: [z 8][oh 2][kc 64][16KB slab image]; image = 16 chunks(16 o-rows)
// x swizzled slots. Slab (z,oh,kc) holds hidden[o in oh*256..+256][k=kc*32..+32].
// ---------------------------------------------------------------------------
__global__ __launch_bounds__(256) void gemm1_kernel(
    const u16* __restrict__ A,   // Wt [512][512]
    const u16* __restrict__ Bt,  // text_bf [16384][512]
    const float* __restrict__ bias, const float* __restrict__ a_src,
    const float* __restrict__ a_dst, u16* __restrict__ hS,
    float* __restrict__ s, float* __restrict__ d) {
  __shared__ u16 Alds[128 * 32];
  __shared__ u16 Blds[128 * 32];

  const int bn = blockIdx.x, bm_ = blockIdx.y;
  const int t = threadIdx.x, wave = t >> 6, lane = t & 63;
  const int wm = (wave >> 1) * 64, wn = (wave & 1) * 64;

  f32x4 acc[4][4];
#pragma unroll
  for (int i = 0; i < 4; ++i)
#pragma unroll
    for (int j = 0; j < 4; ++j) acc[i][j] = (f32x4){0.f, 0.f, 0.f, 0.f};

  const int rowA0 = bm_ * 128, rowB0 = bn * 128;
  const int srow = (lane >> 2);
  const int scol = (lane & 3) * 8;

  for (int kt = 0; kt < NF; kt += 32) {
#pragma unroll
    for (int q = 0; q < 2; ++q) {
      int r = wave * 32 + q * 16;
      gl2lds16(A + (size_t)(rowA0 + r + srow) * NF + (kt + scol), &Alds[r * 32]);
    }
#pragma unroll
    for (int q = 0; q < 2; ++q) {
      int r = wave * 32 + q * 16;
      gl2lds16(Bt + (size_t)(rowB0 + r + srow) * NF + (kt + scol), &Blds[r * 32]);
    }
    __syncthreads();

    const int fr = lane & 15;
    const int k0 = (lane >> 4) * 8;
    bf16x8 af[4], bfr[4];
#pragma unroll
    for (int i = 0; i < 4; ++i)
      af[i] = *(const bf16x8*)&Alds[(wm + i * 16 + fr) * 32 + k0];
#pragma unroll
    for (int j = 0; j < 4; ++j)
      bfr[j] = *(const bf16x8*)&Blds[(wn + j * 16 + fr) * 32 + k0];
#pragma unroll
    for (int i = 0; i < 4; ++i)
#pragma unroll
      for (int j = 0; j < 4; ++j)
        acc[i][j] = __builtin_amdgcn_mfma_f32_16x16x32_bf16(af[i], bfr[j],
                                                            acc[i][j], 0, 0, 0);
    __syncthreads();
  }

  const int quad = lane >> 4, ln16 = lane & 15;
  float sa[4] = {0.f, 0.f, 0.f, 0.f}, da[4] = {0.f, 0.f, 0.f, 0.f};
#pragma unroll
  for (int i = 0; i < 4; ++i) {
    int m0 = bm_ * 128 + wm + i * 16 + quad * 4;
#pragma unroll
    for (int r = 0; r < 4; ++r) {
      int m = m0 + r;
      float bv = bias[m];
      float asv = a_src[m], adv = a_dst[m];
      int oh = m >> 8, och = (m >> 4) & 15, rc = m & 15;
#pragma unroll
      for (int j = 0; j < 4; ++j) {
        int n = bn * 128 + wn + j * 16 + ln16;
        float h = acc[i][j][r] + bv;
        int zz = n >> 11, nz = n & 2047;
        int kc = nz >> 5, kin = nz & 31;
        size_t off = ((((size_t)zz * 2 + oh) * 64 + kc) << 13)  // slab, u16 units
                     + (och << 9)
                     + ((size_t)(rc * 4 + ((kin >> 3) ^ ((rc >> 1) & 3))) << 3)
                     + (kin & 7);
        hS[off] = f2bf(h);
        sa[j] = fmaf(h, asv, sa[j]);
        da[j] = fmaf(h, adv, da[j]);
      }
    }
  }
#pragma unroll
  for (int j = 0; j < 4; ++j) {
    float v = sa[j] + __shfl_xor(sa[j], 16, 64);
    v += __shfl_xor(v, 32, 64);
    float w2 = da[j] + __shfl_xor(da[j], 16, 64);
    w2 += __shfl_xor(w2, 32, 64);
    if (quad == 0) {
      int n = bn * 128 + wn + j * 16 + ln16;
      atomicAdd(&s[n], v);
      atomicAdd(&d[n], w2);
    }
  }
}

// ---------------------------------------------------------------------------
// K4 (fused): out[z,i,o] = (1/l_i)*sum_j exp(lrelu(s_i+d_j))·[!adj]·h[j][o]
// 64(i) x 256(o) tile, 4 waves (each 64x64), BK=64, grid (32,2,8)=512 blocks.
// B staged from pre-swizzled slabs: every global_load_lds reads 1 KB CONTIGUOUS.
// Mask from 4 MB bitmask (L2-hot). P generated in-register -> swizzled LDS.
// ---------------------------------------------------------------------------
__global__ __launch_bounds__(256, 2) void fused_attn_kernel(
    const uint32_t* __restrict__ bm, const float* __restrict__ s,
    const float* __restrict__ d, const u16* __restrict__ hS,
    float* __restrict__ out) {
  __shared__ u16 Blds[16384];      // 32 KB = 2 kc-slabs
  __shared__ u16 Plds[4096];       // 8 KB = 2 k-half images (64 rows each... 4KB per 32-k)
  __shared__ float lpart[256];
  __shared__ float linv_lds[64];

  const int z = blockIdx.z, oh = blockIdx.y;
  const int i0 = blockIdx.x * 64;
  const int t = threadIdx.x, wave = t >> 6, lane = t & 63;
  const int quad = lane >> 4, ln16 = lane & 15;

  // P-gen mapping: 4 threads per i-row, 16 k each
  const int pr = t >> 2;           // 0..63
  const int ko = (t & 3) * 16;     // 0,16,32,48
  const float si = s[z * NN + i0 + pr];
  const uint32_t* bmrow = bm + (size_t)(z * NN + i0 + pr) * 64;
  const float* db = d + z * NN;

  const char* slabB = (const char*)hS + (size_t)(z * 2 + oh) * 1048576;

  f32x4 acc[4][4];
#pragma unroll
  for (int i = 0; i < 4; ++i)
#pragma unroll
    for (int j = 0; j < 4; ++j) acc[i][j] = (f32x4){0.f, 0.f, 0.f, 0.f};

  // prefetch regs for kt=0
  uint32_t bw = bmrow[ko >> 5];
  float4 dv[4];
#pragma unroll
  for (int c = 0; c < 4; ++c) dv[c] = *(const float4*)&db[ko + c * 4];

  const int fslot = ln16 * 4 + (quad ^ ((ln16 >> 1) & 3));
  const int prc = pr & 15, pch = pr >> 4;
  const int ph = ko >> 5, pq0 = (ko >> 3) & 3;  // k-half, first quarter (0 or 2)
  char* pbase = (char*)Plds + ph * 4096 + pch * 1024;
  char* pdst0 = pbase + (prc * 4 + (pq0 ^ ((prc >> 1) & 3))) * 16;
  char* pdst1 = pbase + (prc * 4 + ((pq0 + 1) ^ ((prc >> 1) & 3))) * 16;

  float lsum = 0.f;

  for (int kt = 0; kt < NN; kt += 64) {
    // ---- P values for k = kt+ko .. +16 from prefetched regs ----
    uint32_t bits16 = (bw >> (ko & 16)) & 0xFFFFu;
    u16 pk[16];
#pragma unroll
    for (int cc = 0; cc < 4; ++cc) {
      float4 dq = dv[cc];
#pragma unroll
      for (int e = 0; e < 4; ++e) {
        float dj = (e == 0) ? dq.x : (e == 1) ? dq.y : (e == 2) ? dq.z : dq.w;
        float x = si + dj;
        float xm = fmaxf(x, 0.2f * x);
        float p = ((bits16 >> (cc * 4 + e)) & 1u) ? 0.f : __expf(xm);
        lsum += p;
        pk[cc * 4 + e] = f2bf(p);
      }
    }

    __syncthreads();  // (1) frags of previous iter consumed

    *(int4*)pdst0 = *(int4*)&pk[0];
    *(int4*)pdst1 = *(int4*)&pk[8];

    // ---- stage 2 contiguous 16 KB slabs (kc0, kc0+1) ----
    {
      const char* gB = slabB + (size_t)kt * 512;  // kt/64 * 32768
#pragma unroll
      for (int c = 0; c < 8; ++c) {
        int boff = (c * 4 + wave) * 1024;
        gl2lds16(gB + boff + lane * 16, (char*)Blds + boff);
      }
    }
    __syncthreads();  // (2) P visible + B staged

    // ---- prefetch next kt (L2-hot, overlaps MFMA) ----
    if (kt + 64 < NN) {
      bw = bmrow[((kt + 64) >> 5) + (ko >> 5)];
#pragma unroll
      for (int c = 0; c < 4; ++c)
        dv[c] = *(const float4*)&db[kt + 64 + ko + c * 4];
    }

    // ---- fragments + MFMA: 2 k-halves x 4i x 4j ----
#pragma unroll
    for (int h = 0; h < 2; ++h) {
      bf16x8 af[4], bfv[4];
#pragma unroll
      for (int i = 0; i < 4; ++i)
        af[i] = *(const bf16x8*)((const char*)Plds + h * 4096 + i * 1024 + fslot * 16);
#pragma unroll
      for (int j = 0; j < 4; ++j)
        bfv[j] = *(const bf16x8*)((const char*)Blds + h * 16384 +
                                  (wave * 4 + j) * 1024 + fslot * 16);
#pragma unroll
      for (int i = 0; i < 4; ++i)
#pragma unroll
        for (int j = 0; j < 4; ++j)
          acc[i][j] = __builtin_amdgcn_mfma_f32_16x16x32_bf16(af[i], bfv[j],
                                                              acc[i][j], 0, 0, 0);
    }
  }

  // ---- row sums -> 1/l (block covers full K, sums complete) ----
  lpart[pr * 4 + (t & 3)] = lsum;
  __syncthreads();
  if (t < 64) {
    const float* lp = &lpart[t * 4];
    linv_lds[t] = 1.0f / ((lp[0] + lp[1]) + (lp[2] + lp[3]));
  }
  __syncthreads();

  // ---- epilogue: C/D layout col=lane&15, row=quad*4+reg ----
#pragma unroll
  for (int i = 0; i < 4; ++i) {
#pragma unroll
    for (int r = 0; r < 4; ++r) {
      int m = i * 16 + quad * 4 + r;
      float sc = linv_lds[m];
      float* ob = out + ((size_t)(z * NN) + i0 + m) * NF + oh * 256 + wave * 64;
#pragma unroll
      for (int j = 0; j < 4; ++j) ob[j * 16 + ln16] = acc[i][j][r] * sc;
    }
  }
}

// ---------------------------------------------------------------------------
// launch
// ---------------------------------------------------------------------------
extern "C" void kernel_launch(void* const* d_in, const int* in_sizes, int n_in,
                              void* d_out, int out_size, void* d_ws,
                              size_t ws_size, hipStream_t stream) {
  const float* text  = (const float*)d_in[0];   // [8,2048,512] fp32
  const int*   adj   = (const int*)d_in[1];     // [8,2048,2048] int32
  const float* W     = (const float*)d_in[2];   // [512,512] fp32
  const float* bias  = (const float*)d_in[3];   // [512] fp32
  const float* a_src = (const float*)d_in[4];   // [512] fp32
  const float* a_dst = (const float*)d_in[5];   // [512] fp32
  float* out = (float*)d_out;                   // [8,2048,512] fp32

  // ws layout (bytes), ~37.2 MB
  char* ws = (char*)d_ws;
  u16*      text_bf = (u16*)(ws + 0);            // 16,777,216
  u16*      Wt      = (u16*)(ws + 16777216);     //    524,288
  u16*      hS      = (u16*)(ws + 17301504);     // 16,777,216  slabs
  float*    s       = (float*)(ws + 34078720);   //     65,536
  float*    d       = (float*)(ws + 34144256);   //     65,536
  uint32_t* bmask   = (uint32_t*)(ws + 34209792);// 4,194,304

  hipMemsetAsync(s, 0, 131072, stream);          // zero s,d (contiguous)

  conv_kernel<<<9216, 256, 0, stream>>>(text, W, text_bf, Wt);
  pack_kernel<<<4096, 256, 0, stream>>>(adj, bmask);

  gemm1_kernel<<<dim3(128, 4, 1), 256, 0, stream>>>(Wt, text_bf, bias, a_src,
                                                    a_dst, hS, s, d);

  fused_attn_kernel<<<dim3(NN / 64, 2, NB), 256, 0, stream>>>(bmask, s, d, hS,
                                                              out);
}